// Round 12
// baseline (543.896 us; speedup 1.0000x reference)
//
#include <hip/hip_runtime.h>
#include <hip/hip_bf16.h>
#include <hip/hip_fp16.h>

#define N_NODES 50000
#define N_EDGES 500000
#define HEADS 8
#define HID 64
#define HD 512   // HEADS*HID
#define NCLS 10
#define M_PAD 50048  // 391*128
#define YTILES_L1 391
#define F0ROWS 30080  // 235*128
#define F1ROWS 20096  // 157*128

typedef _Float16 f16x8 __attribute__((ext_vector_type(8)));
typedef _Float16 h8v   __attribute__((ext_vector_type(8)));
typedef float    f32x4 __attribute__((ext_vector_type(4)));

#define GLD_LDS16(g, l) __builtin_amdgcn_global_load_lds( \
    (__attribute__((address_space(1))) void*)(g),         \
    (__attribute__((address_space(3))) void*)(l), 16, 0, 0)

// ---------------------------------------------------------------------------
// prep: one launch, grid-strided sections.
//  E: f0h = f16(feat0) padded to F0ROWS        F: f1h = f16(feat1) padded
//  A: Wc0t[n*256+k] = f16(sum_j fc0_w[k][j] * W0[j][n])   (fc folded into W0)
//  B: Wc1t[n*128+k] = f16(sum_j fc1_w[k][j] * W0[j][n])
//  C: W1t[n*512+k]  = f16(W1[k][n])
//  D: biasF[t*512+n] = sum_j fc{t}_b[j] * W0[j][n]
//  G: cnt zero
// ---------------------------------------------------------------------------
#define E_N (F0ROWS * 256)
#define F_N (F1ROWS * 128)
#define A_N (512 * 256)
#define B_N (512 * 128)
#define C_N (512 * 512)
#define D_N 1024
#define PREP_TOTAL (E_N + F_N + A_N + B_N + C_N + D_N + N_NODES)

__global__ void prep(const float* __restrict__ feat0, const float* __restrict__ feat1,
                     const float* __restrict__ fc0_w, const float* __restrict__ fc0_b,
                     const float* __restrict__ fc1_w, const float* __restrict__ fc1_b,
                     const float* __restrict__ W0, const float* __restrict__ W1,
                     _Float16* __restrict__ f0h, _Float16* __restrict__ f1h,
                     _Float16* __restrict__ Wc0t, _Float16* __restrict__ Wc1t,
                     _Float16* __restrict__ W1t, float* __restrict__ biasF,
                     int* __restrict__ cnt) {
    int idx = blockIdx.x * 256 + threadIdx.x;
    if (idx < E_N) {
        int m = idx >> 8, k = idx & 255;
        f0h[idx] = (m < 30000) ? (_Float16)feat0[(size_t)m * 256 + k] : (_Float16)0.f;
        return;
    }
    idx -= E_N;
    if (idx < F_N) {
        int m = idx >> 7, k = idx & 127;
        f1h[idx] = (m < 20000) ? (_Float16)feat1[(size_t)m * 128 + k] : (_Float16)0.f;
        return;
    }
    idx -= F_N;
    if (idx < A_N) {     // idx = k*512 + n, k<256
        int k = idx >> 9, n = idx & 511;
        float s = 0.f;
#pragma unroll 8
        for (int j = 0; j < 64; j++) s += fc0_w[k * 64 + j] * W0[j * 512 + n];
        Wc0t[n * 256 + k] = (_Float16)s;
        return;
    }
    idx -= A_N;
    if (idx < B_N) {     // idx = k*512 + n, k<128
        int k = idx >> 9, n = idx & 511;
        float s = 0.f;
#pragma unroll 8
        for (int j = 0; j < 64; j++) s += fc1_w[k * 64 + j] * W0[j * 512 + n];
        Wc1t[n * 128 + k] = (_Float16)s;
        return;
    }
    idx -= B_N;
    if (idx < C_N) {     // idx = k*512 + n
        int k = idx >> 9, n = idx & 511;
        W1t[n * 512 + k] = (_Float16)W1[k * 512 + n];
        return;
    }
    idx -= C_N;
    if (idx < D_N) {     // idx = t*512 + n
        int t = idx >> 9, n = idx & 511;
        const float* fb = t ? fc1_b : fc0_b;
        float s = 0.f;
#pragma unroll 8
        for (int j = 0; j < 64; j++) s += fb[j] * W0[j * 512 + n];
        biasF[t * 512 + n] = s;
        return;
    }
    idx -= D_N;
    if (idx < N_NODES) cnt[idx] = 0;
}

// ---------------------------------------------------------------------------
// CSR build: count -> parallel scan (3 kernels) -> scatter
// ---------------------------------------------------------------------------
#define NBLK_SCAN 196  // ceil(50000/256)

__global__ void count_kernel(const int* __restrict__ dst, int* __restrict__ cnt) {
    int t = blockIdx.x * blockDim.x + threadIdx.x;
    if (t < N_EDGES) atomicAdd(&cnt[dst[t]], 1);
}

__global__ void scan_part(const int* __restrict__ cnt, int* __restrict__ part) {
    __shared__ int s[256];
    int i = blockIdx.x * 256 + threadIdx.x;
    s[threadIdx.x] = (i < N_NODES) ? cnt[i] : 0;
    __syncthreads();
    for (int off = 128; off; off >>= 1) {
        if (threadIdx.x < off) s[threadIdx.x] += s[threadIdx.x + off];
        __syncthreads();
    }
    if (threadIdx.x == 0) part[blockIdx.x] = s[0];
}

__global__ void scan_offs(int* __restrict__ part) {
    __shared__ int s[256];
    int tid = threadIdx.x;
    int v = (tid < NBLK_SCAN) ? part[tid] : 0;
    s[tid] = v;
    __syncthreads();
    for (int off = 1; off < 256; off <<= 1) {
        int x = (tid >= off) ? s[tid - off] : 0;
        __syncthreads();
        s[tid] += x;
        __syncthreads();
    }
    if (tid < NBLK_SCAN) part[tid] = s[tid] - v;  // exclusive
}

__global__ void scan_apply(const int* __restrict__ cnt, const int* __restrict__ part,
                           int* __restrict__ rp, int* __restrict__ cur) {
    __shared__ int s[256];
    int tid = threadIdx.x;
    int i = blockIdx.x * 256 + tid;
    int v = (i < N_NODES) ? cnt[i] : 0;
    s[tid] = v;
    __syncthreads();
    for (int off = 1; off < 256; off <<= 1) {
        int x = (tid >= off) ? s[tid - off] : 0;
        __syncthreads();
        s[tid] += x;
        __syncthreads();
    }
    if (i < N_NODES) {
        int excl = s[tid] - v + part[blockIdx.x];
        rp[i] = excl; cur[i] = excl;
    }
    if (i == 0) rp[N_NODES] = N_EDGES;
}

__global__ void scatter_kernel(const int* __restrict__ src, const int* __restrict__ dst,
                               int* __restrict__ cursor, int* __restrict__ src_sorted) {
    int t = blockIdx.x * blockDim.x + threadIdx.x;
    if (t >= N_EDGES) return;
    int pos = atomicAdd(&cursor[dst[t]], 1);
    src_sorted[pos] = src[t];
}

// ---------------------------------------------------------------------------
// Wide f16 MFMA GEMM: 128x256 tile, 512 threads (8 waves), BK=32, XOR-4
// kgroup swizzle; XCD co-location via bid mod 8 decode.
// Optional fused column-bias (cbias, fp32) added before C-write and el/er.
// Fused epilogue: el/er per (row, head); each wave's 64 cols = 1 head.
// C/el/er rows written at row_off offset.
// ---------------------------------------------------------------------------
__global__ __launch_bounds__(512) void gemm_mfma_wide(const _Float16* __restrict__ A,
                                                      const _Float16* __restrict__ Bt,
                                                      _Float16* __restrict__ Cb,
                                                      const float* __restrict__ al,
                                                      const float* __restrict__ ar,
                                                      const float* __restrict__ cbias,
                                                      float* __restrict__ el,
                                                      float* __restrict__ er,
                                                      int M, int K, int row_off, int ytiles) {
    __shared__ _Float16 Asl[128 * 32];
    __shared__ _Float16 Bsl[256 * 32];
    int bid = blockIdx.x;
    int k8 = bid & 7, jj = bid >> 3;
    int y = k8 + 8 * (jj >> 1);
    if (y >= ytiles) return;
    int m0 = y * 128;
    int n0 = (jj & 1) * 256;
    int t = threadIdx.x;
    int lane = t & 63;
    int w = t >> 6;
    int wm = (w & 1) * 64, wn = (w >> 1) * 64;
    int l15 = lane & 15, quad = lane >> 4;
    f32x4 acc[4][4];
#pragma unroll
    for (int i = 0; i < 4; i++)
#pragma unroll
        for (int j = 0; j < 4; j++) acc[i][j] = (f32x4){0.f, 0.f, 0.f, 0.f};

    int fbA = t * 16;
    int rowA = fbA >> 6, kgA = ((fbA >> 4) & 3) ^ (rowA & 3);
    int fbB0 = t * 16;
    int fbB1 = fbB0 + 8192;
    int rowB0 = fbB0 >> 6, kgB0 = ((fbB0 >> 4) & 3) ^ (rowB0 & 3);
    int rowB1 = fbB1 >> 6, kgB1 = ((fbB1 >> 4) & 3) ^ (rowB1 & 3);

    for (int k0 = 0; k0 < K; k0 += 32) {
        GLD_LDS16(A + (size_t)(m0 + rowA) * K + k0 + kgA * 8, (char*)Asl + fbA);
        GLD_LDS16(Bt + (size_t)(n0 + rowB0) * K + k0 + kgB0 * 8, (char*)Bsl + fbB0);
        GLD_LDS16(Bt + (size_t)(n0 + rowB1) * K + k0 + kgB1 * 8, (char*)Bsl + fbB1);
        __syncthreads();
        f16x8 af[4], bfr[4];
#pragma unroll
        for (int i = 0; i < 4; i++) {
            int r = wm + i * 16 + l15;
            int kg = quad ^ (r & 3);
            af[i] = *(const f16x8*)(Asl + r * 32 + kg * 8);
        }
#pragma unroll
        for (int j = 0; j < 4; j++) {
            int r = wn + j * 16 + l15;
            int kg = quad ^ (r & 3);
            bfr[j] = *(const f16x8*)(Bsl + r * 32 + kg * 8);
        }
#pragma unroll
        for (int i = 0; i < 4; i++)
#pragma unroll
            for (int j = 0; j < 4; j++)
                acc[i][j] = __builtin_amdgcn_mfma_f32_16x16x32_f16(af[i], bfr[j], acc[i][j], 0, 0, 0);
        __syncthreads();
    }
    // column bias (fp32), 4 cols per lane
    float cb[4];
#pragma unroll
    for (int j = 0; j < 4; j++)
        cb[j] = cbias ? cbias[n0 + wn + j * 16 + l15] : 0.f;
    // C/D layout: col = l15, row = quad*4 + reg  [m89/m91 verified]
#pragma unroll
    for (int i = 0; i < 4; i++) {
        int rbase = m0 + wm + i * 16 + quad * 4;
#pragma unroll
        for (int j = 0; j < 4; j++) {
            int col = n0 + wn + j * 16 + l15;
#pragma unroll
            for (int r = 0; r < 4; r++) {
                int row = rbase + r;
                if (row < M)
                    Cb[(size_t)(row_off + row) * HD + col] = (_Float16)(acc[i][j][r] + cb[j]);
            }
        }
    }
    int h = (n0 + wn) >> 6;
    float alv[4], arv[4];
#pragma unroll
    for (int j = 0; j < 4; j++) {
        alv[j] = al[h * 64 + j * 16 + l15];
        arv[j] = ar[h * 64 + j * 16 + l15];
    }
#pragma unroll
    for (int i = 0; i < 4; i++) {
#pragma unroll
        for (int r = 0; r < 4; r++) {
            float sl = 0.f, sr = 0.f;
#pragma unroll
            for (int j = 0; j < 4; j++) {
                float v = acc[i][j][r] + cb[j];
                sl += v * alv[j]; sr += v * arv[j];
            }
#pragma unroll
            for (int mk = 1; mk < 16; mk <<= 1) {
                sl += __shfl_xor(sl, mk);
                sr += __shfl_xor(sr, mk);
            }
            int row = m0 + wm + i * 16 + quad * 4 + r;
            if (l15 == 0 && row < M) {
                el[(size_t)(row_off + row) * HEADS + h] = sl;
                er[(size_t)(row_off + row) * HEADS + h] = sr;
            }
        }
    }
}

// ---------------------------------------------------------------------------
// Fused edge softmax + aggregation, one wave per block (64 threads).
// Wave-private LDS handoff, no block barrier. Phase B: 4x-unrolled gather.
// ---------------------------------------------------------------------------
__global__ __launch_bounds__(64) void attn_agg(
        const int* __restrict__ rp, const int* __restrict__ srcs,
        const float* __restrict__ el, const float* __restrict__ er,
        const _Float16* __restrict__ feat, const float* __restrict__ bias,
        _Float16* __restrict__ out) {
    __shared__ float aS[592];   // [0..575] alpha (p*9+h), [576..583] inv, [584..591] m
    __shared__ int   sS[64];
    int lane = threadIdx.x;
    int n    = blockIdx.x;
    int s0 = rp[n], s1 = rp[n + 1];
    int deg = s1 - s0;
    float er8[8];
    {
        f32x4 a = *(const f32x4*)(er + (size_t)n * 8);
        f32x4 b = *(const f32x4*)(er + (size_t)n * 8 + 4);
        er8[0]=a[0]; er8[1]=a[1]; er8[2]=a[2]; er8[3]=a[3];
        er8[4]=b[0]; er8[5]=b[1]; er8[6]=b[2]; er8[7]=b[3];
    }
    bool fast = (deg <= 64);
    if (fast) {
        bool act = lane < deg;
        int sp = act ? srcs[s0 + lane] : 0;
        sS[lane] = sp;
        f32x4 ea = {0.f,0.f,0.f,0.f}, eb = {0.f,0.f,0.f,0.f};
        if (act) {
            ea = *(const f32x4*)(el + (size_t)sp * 8);
            eb = *(const f32x4*)(el + (size_t)sp * 8 + 4);
        }
        float e8[8] = {ea[0],ea[1],ea[2],ea[3],eb[0],eb[1],eb[2],eb[3]};
#pragma unroll
        for (int h = 0; h < 8; h++) {
            float e = e8[h] + er8[h];
            e = e > 0.f ? e : 0.2f * e;
            e8[h] = act ? e : -1e30f;
        }
#pragma unroll
        for (int h = 0; h < 8; h++) {
            float mm = e8[h];
#pragma unroll
            for (int mk = 1; mk < 64; mk <<= 1) mm = fmaxf(mm, __shfl_xor(mm, mk));
            float pv = act ? __expf(e8[h] - mm) : 0.f;
            float ss = pv;
#pragma unroll
            for (int mk = 1; mk < 64; mk <<= 1) ss += __shfl_xor(ss, mk);
            aS[lane * 9 + h] = pv * (1.f / fmaxf(ss, 1e-9f));  // pre-scaled alpha
        }
    } else {
        float m8[8], s8[8];
#pragma unroll
        for (int h = 0; h < 8; h++) { m8[h] = -1e30f; s8[h] = 0.f; }
        for (int base = s0; base < s1; base += 64) {
            bool act = base + lane < s1;
            int sp = act ? srcs[base + lane] : 0;
            f32x4 ea = {0.f,0.f,0.f,0.f}, eb = {0.f,0.f,0.f,0.f};
            if (act) {
                ea = *(const f32x4*)(el + (size_t)sp * 8);
                eb = *(const f32x4*)(el + (size_t)sp * 8 + 4);
            }
            float ev[8] = {ea[0],ea[1],ea[2],ea[3],eb[0],eb[1],eb[2],eb[3]};
#pragma unroll
            for (int h = 0; h < 8; h++) {
                float e = ev[h] + er8[h];
                e = e > 0.f ? e : 0.2f * e;
                e = act ? e : -1e30f;
                float cm = e;
#pragma unroll
                for (int mk = 1; mk < 64; mk <<= 1) cm = fmaxf(cm, __shfl_xor(cm, mk));
                float nm = fmaxf(m8[h], cm);
                float pv = act ? __expf(e - nm) : 0.f;
#pragma unroll
                for (int mk = 1; mk < 64; mk <<= 1) pv += __shfl_xor(pv, mk);
                s8[h] = s8[h] * __expf(m8[h] - nm) + pv;
                m8[h] = nm;
            }
        }
        if (lane == 0) {
#pragma unroll
            for (int h = 0; h < 8; h++) {
                aS[576 + h] = 1.f / fmaxf(s8[h], 1e-9f);
                aS[584 + h] = m8[h];
            }
        }
    }
    // wave-private LDS handoff (lockstep wave + compiler lgkmcnt ordering)
    __builtin_amdgcn_wave_barrier();
    int hh = lane >> 3, d0 = (lane & 7) * 8;   // lane*8 = hh*64 + d0
    h8v z = {(_Float16)0, (_Float16)0, (_Float16)0, (_Float16)0,
             (_Float16)0, (_Float16)0, (_Float16)0, (_Float16)0};
    h8v acc0 = z, acc1 = z, acc2 = z, acc3 = z;
    const _Float16* colbase = feat + hh * 64 + d0;
    if (fast) {
        int p = 0;
        for (; p + 4 <= deg; p += 4) {
            int spa = sS[p],     spb = sS[p + 1];
            int spc = sS[p + 2], spd = sS[p + 3];
            _Float16 aa = (_Float16)aS[p * 9 + hh];
            _Float16 ab = (_Float16)aS[(p + 1) * 9 + hh];
            _Float16 ac = (_Float16)aS[(p + 2) * 9 + hh];
            _Float16 ad = (_Float16)aS[(p + 3) * 9 + hh];
            h8v fa = *(const h8v*)(colbase + (size_t)spa * HD);
            h8v fb = *(const h8v*)(colbase + (size_t)spb * HD);
            h8v fc = *(const h8v*)(colbase + (size_t)spc * HD);
            h8v fd = *(const h8v*)(colbase + (size_t)spd * HD);
            h8v a8a = {aa, aa, aa, aa, aa, aa, aa, aa};
            h8v a8b = {ab, ab, ab, ab, ab, ab, ab, ab};
            h8v a8c = {ac, ac, ac, ac, ac, ac, ac, ac};
            h8v a8d = {ad, ad, ad, ad, ad, ad, ad, ad};
            acc0 += a8a * fa;
            acc1 += a8b * fb;
            acc2 += a8c * fc;
            acc3 += a8d * fd;
        }
        for (; p < deg; p++) {
            int sp = sS[p];
            _Float16 ah = (_Float16)aS[p * 9 + hh];
            h8v a8 = {ah, ah, ah, ah, ah, ah, ah, ah};
            h8v f = *(const h8v*)(colbase + (size_t)sp * HD);
            acc0 += a8 * f;
        }
    } else {
        float inv_l = aS[576 + hh];
        float m_l   = aS[584 + hh];
        float ern_l = er[(size_t)n * 8 + hh];
        for (int p = s0; p < s1; p++) {
            int sp = srcs[p];
            float e = el[(size_t)sp * 8 + hh] + ern_l;
            e = e > 0.f ? e : 0.2f * e;
            _Float16 ah = (_Float16)(__expf(e - m_l) * inv_l);
            h8v a8 = {ah, ah, ah, ah, ah, ah, ah, ah};
            h8v f = *(const h8v*)(colbase + (size_t)sp * HD);
            acc0 += a8 * f;
        }
    }
    acc0 += acc1; acc2 += acc3; acc0 += acc2;
    float4 b0v = *(const float4*)(bias + lane * 8);
    float4 b1v = *(const float4*)(bias + lane * 8 + 4);
    float bb[8] = {b0v.x,b0v.y,b0v.z,b0v.w,b1v.x,b1v.y,b1v.z,b1v.w};
    h8v o;
#pragma unroll
    for (int j = 0; j < 8; j++) {
        float x = (float)acc0[j] + bb[j];
        x = x > 0.f ? x : __expf(x) - 1.f;
        o[j] = (_Float16)x;
    }
    *(h8v*)(out + (size_t)n * HD + lane * 8) = o;
}

// ---------------------------------------------------------------------------
// layer 2 GEMM (N=10) from f16 A, fused el2/er2 epilogue
// ---------------------------------------------------------------------------
__global__ __launch_bounds__(256) void gemm_n10v2(
        const _Float16* __restrict__ A, const float* __restrict__ B,
        const float* __restrict__ al2, const float* __restrict__ ar2,
        float* __restrict__ C, float* __restrict__ el, float* __restrict__ er) {
    __shared__ float Bs[512 * 11];
    int t = threadIdx.x;
    for (int i = t; i < 512 * NCLS; i += 256) {
        int k = i / NCLS, c = i - k * NCLS;
        Bs[k * 11 + c] = B[i];
    }
    __syncthreads();
    int lane = t & 63;
    int m = blockIdx.x * 4 + (t >> 6);
    float acc[NCLS];
#pragma unroll
    for (int c = 0; c < NCLS; c++) acc[c] = 0.f;
    const _Float16* a = A + (size_t)m * HD;
#pragma unroll
    for (int j = 0; j < 8; j++) {
        float av = (float)a[j * 64 + lane];
        const float* br = Bs + (j * 64 + lane) * 11;
#pragma unroll
        for (int c = 0; c < NCLS; c++) acc[c] += av * br[c];
    }
#pragma unroll
    for (int c = 0; c < NCLS; c++)
#pragma unroll
        for (int mk = 1; mk < 64; mk <<= 1) acc[c] += __shfl_xor(acc[c], mk);
    if (lane == 0) {
        float e1 = 0.f, e2 = 0.f;
#pragma unroll
        for (int c = 0; c < NCLS; c++) { e1 += acc[c] * al2[c]; e2 += acc[c] * ar2[c]; }
        el[m] = e1; er[m] = e2;
#pragma unroll
        for (int c = 0; c < NCLS; c++) C[(size_t)m * NCLS + c] = acc[c];
    }
}

// ---------------------------------------------------------------------------
// layer 2 fused softmax+aggregation (H=1, D=10), one wave per block
// ---------------------------------------------------------------------------
__global__ __launch_bounds__(64) void attn2_agg2(
        const int* __restrict__ rp, const int* __restrict__ srcs,
        const float* __restrict__ el, const float* __restrict__ er,
        const float* __restrict__ feat2, const float* __restrict__ b2,
        float* __restrict__ out) {
    int lane = threadIdx.x;
    int n = blockIdx.x;
    int s0 = rp[n], s1 = rp[n + 1], deg = s1 - s0;
    float ern = er[n];
    float facc[NCLS];
#pragma unroll
    for (int c = 0; c < NCLS; c++) facc[c] = 0.f;
    if (deg <= 64) {
        bool act = lane < deg;
        int sp = act ? srcs[s0 + lane] : 0;
        float e = act ? el[sp] + ern : 0.f;
        e = e > 0.f ? e : 0.2f * e;
        if (!act) e = -1e30f;
        float mm = e;
#pragma unroll
        for (int mk = 1; mk < 64; mk <<= 1) mm = fmaxf(mm, __shfl_xor(mm, mk));
        float pv = act ? __expf(e - mm) : 0.f;
        float ss = pv;
#pragma unroll
        for (int mk = 1; mk < 64; mk <<= 1) ss += __shfl_xor(ss, mk);
        float a = pv / fmaxf(ss, 1e-9f);
        if (act) {
#pragma unroll
            for (int c = 0; c < NCLS; c++) facc[c] = a * feat2[(size_t)sp * NCLS + c];
        }
    } else {
        float mm = -1e30f, ssum = 0.f;
        for (int base = s0; base < s1; base += 64) {
            bool act = base + lane < s1;
            int sp = act ? srcs[base + lane] : 0;
            float e = act ? el[sp] + ern : 0.f;
            e = e > 0.f ? e : 0.2f * e;
            if (!act) e = -1e30f;
            float cm = e;
#pragma unroll
            for (int mk = 1; mk < 64; mk <<= 1) cm = fmaxf(cm, __shfl_xor(cm, mk));
            float nm = fmaxf(mm, cm);
            float pv = act ? __expf(e - nm) : 0.f;
#pragma unroll
            for (int mk = 1; mk < 64; mk <<= 1) pv += __shfl_xor(pv, mk);
            ssum = ssum * __expf(mm - nm) + pv;
            mm = nm;
        }
        float inv = 1.f / fmaxf(ssum, 1e-9f);
        for (int base = s0; base < s1; base += 64) {
            bool act = base + lane < s1;
            int sp = act ? srcs[base + lane] : 0;
            float e = act ? el[sp] + ern : 0.f;
            e = e > 0.f ? e : 0.2f * e;
            float a = act ? __expf(e - mm) * inv : 0.f;
            if (act) {
#pragma unroll
                for (int c = 0; c < NCLS; c++) facc[c] += a * feat2[(size_t)sp * NCLS + c];
            }
        }
    }
#pragma unroll
    for (int c = 0; c < NCLS; c++)
#pragma unroll
        for (int mk = 1; mk < 64; mk <<= 1) facc[c] += __shfl_xor(facc[c], mk);
    if (lane == 0) {
#pragma unroll
        for (int c = 0; c < NCLS; c++) out[(size_t)n * NCLS + c] = facc[c] + b2[c];
    }
}

// ---------------------------------------------------------------------------
extern "C" void kernel_launch(void* const* d_in, const int* in_sizes, int n_in,
                              void* d_out, int out_size, void* d_ws, size_t ws_size,
                              hipStream_t stream) {
    const float* feat0 = (const float*)d_in[0];
    const float* feat1 = (const float*)d_in[1];
    const float* fc0_w = (const float*)d_in[2];
    const float* fc0_b = (const float*)d_in[3];
    const float* fc1_w = (const float*)d_in[4];
    const float* fc1_b = (const float*)d_in[5];
    const float* W0    = (const float*)d_in[6];
    const float* al0   = (const float*)d_in[7];
    const float* ar0   = (const float*)d_in[8];
    const float* b0    = (const float*)d_in[9];
    const float* W1    = (const float*)d_in[10];
    const float* al1   = (const float*)d_in[11];
    const float* ar1   = (const float*)d_in[12];
    const float* b1    = (const float*)d_in[13];
    const float* W2    = (const float*)d_in[14];
    const float* al2   = (const float*)d_in[15];
    const float* ar2   = (const float*)d_in[16];
    const float* b2    = (const float*)d_in[17];
    const int* eidx    = (const int*)d_in[18];
    const int* src = eidx;
    const int* dst = eidx + N_EDGES;
    float* out = (float*)d_out;

    char* ws = (char*)d_ws;
    size_t off = 0;
    auto alloc = [&](size_t bytes) { size_t o = off; off = (off + bytes + 255) & ~(size_t)255; return o; };

    _Float16* featA = (_Float16*)(ws + alloc((size_t)M_PAD * HD * 2));
    _Float16* aggh  = (_Float16*)(ws + alloc((size_t)M_PAD * HD * 2));
    _Float16* f0h   = (_Float16*)(ws + alloc((size_t)F0ROWS * 256 * 2));
    _Float16* f1h   = (_Float16*)(ws + alloc((size_t)F1ROWS * 128 * 2));
    float*    feat2 = (float*)(ws + alloc((size_t)N_NODES * NCLS * 4));
    float*    el    = (float*)(ws + alloc((size_t)N_NODES * HEADS * 4));
    float*    er    = (float*)(ws + alloc((size_t)N_NODES * HEADS * 4));
    float*    el2   = (float*)(ws + alloc((size_t)N_NODES * 4));
    float*    er2   = (float*)(ws + alloc((size_t)N_NODES * 4));
    float*    biasF = (float*)(ws + alloc(1024 * 4));
    int*      cnt   = (int*)  (ws + alloc((size_t)N_NODES * 4));
    int*      rp    = (int*)  (ws + alloc((size_t)(N_NODES + 1) * 4));
    int*      cur   = (int*)  (ws + alloc((size_t)N_NODES * 4));
    int*      srcs  = (int*)  (ws + alloc((size_t)N_EDGES * 4));
    int*      part  = (int*)  (ws + alloc(1024));
    _Float16* Wc0t  = (_Float16*)(ws + alloc(512 * 256 * 2));
    _Float16* Wc1t  = (_Float16*)(ws + alloc(512 * 128 * 2));
    _Float16* W1t   = (_Float16*)(ws + alloc(512 * 512 * 2));

    // --- prep: fc-fold weights, input casts, W1 transpose, biases, cnt zero ---
    prep<<<(PREP_TOTAL + 255) / 256, 256, 0, stream>>>(
        feat0, feat1, fc0_w, fc0_b, fc1_w, fc1_b, W0, W1,
        f0h, f1h, Wc0t, Wc1t, W1t, biasF, cnt);

    // --- CSR build ---
    count_kernel<<<(N_EDGES + 255) / 256, 256, 0, stream>>>(dst, cnt);
    scan_part<<<NBLK_SCAN, 256, 0, stream>>>(cnt, part);
    scan_offs<<<1, 256, 0, stream>>>(part);
    scan_apply<<<NBLK_SCAN, 256, 0, stream>>>(cnt, part, rp, cur);
    scatter_kernel<<<(N_EDGES + 255) / 256, 256, 0, stream>>>(src, dst, cur, srcs);

    // --- layer 0: two fc-folded MFMA GEMMs (type 0: K=256, type 1: K=128) ---
    int g0a = 8 * 2 * ((235 + 7) / 8);   // 480  (235 y-tiles)
    int g0b = 8 * 2 * ((157 + 7) / 8);   // 320  (157 y-tiles)
    int g1  = 8 * 2 * ((YTILES_L1 + 7) / 8);  // 784
    gemm_mfma_wide<<<g0a, 512, 0, stream>>>(f0h, Wc0t, featA, al0, ar0, biasF,
                                            el, er, 30000, 256, 0, 235);
    gemm_mfma_wide<<<g0b, 512, 0, stream>>>(f1h, Wc1t, featA, al0, ar0, biasF + 512,
                                            el, er, 20000, 128, 30000, 157);
    attn_agg<<<N_NODES, 64, 0, stream>>>(rp, srcs, el, er, featA, b0, aggh);

    // --- layer 1 ---
    gemm_mfma_wide<<<g1, 512, 0, stream>>>(aggh, W1t, featA, al1, ar1, nullptr,
                                           el, er, N_NODES, HD, 0, YTILES_L1);
    attn_agg<<<N_NODES, 64, 0, stream>>>(rp, srcs, el, er, featA, b1, aggh);

    // --- layer 2 ---
    gemm_n10v2<<<N_NODES / 4, 256, 0, stream>>>(aggh, W2, al2, ar2, feat2, el2, er2);
    attn2_agg2<<<N_NODES, 64, 0, stream>>>(rp, srcs, el2, er2, feat2, b2, out);
}

// Round 13
// 521.990 us; speedup vs baseline: 1.0420x; 1.0420x over previous
//
#include <hip/hip_runtime.h>
#include <hip/hip_bf16.h>
#include <hip/hip_fp16.h>

#define N_NODES 50000
#define N_EDGES 500000
#define HEADS 8
#define HID 64
#define HD 512   // HEADS*HID
#define NCLS 10
#define M_PAD 50048  // 391*128
#define YTILES_L1 391
#define F0ROWS 30080  // 235*128
#define F1ROWS 20096  // 157*128

typedef _Float16 f16x8 __attribute__((ext_vector_type(8)));
typedef _Float16 h8v   __attribute__((ext_vector_type(8)));
typedef float    f32x4 __attribute__((ext_vector_type(4)));

#define GLD_LDS16(g, l) __builtin_amdgcn_global_load_lds( \
    (__attribute__((address_space(1))) void*)(g),         \
    (__attribute__((address_space(3))) void*)(l), 16, 0, 0)

// ---------------------------------------------------------------------------
// prep: one launch, grid-strided sections (count fused in; cnt pre-zeroed by
// hipMemsetAsync).
//  E: f0h = f16(feat0) padded     F: f1h = f16(feat1) padded
//  A: Wc0t[n*256+k] = f16(sum_j fc0_w[k][j]*W0[j][n])  (fc folded into W0)
//  B: Wc1t[n*128+k] = f16(sum_j fc1_w[k][j]*W0[j][n])
//  C: W1t[n*512+k]  = f16(W1[k][n])
//  D: biasF[t*512+n] = fc{t}_b @ W0
//  H: count: atomicAdd(cnt[dst[e]])   (latency-bound, overlaps with copies)
// ---------------------------------------------------------------------------
#define E_N (F0ROWS * 256)
#define F_N (F1ROWS * 128)
#define A_N (512 * 256)
#define B_N (512 * 128)
#define C_N (512 * 512)
#define D_N 1024
#define PREP_TOTAL (E_N + F_N + A_N + B_N + C_N + D_N + N_EDGES)

__global__ void prep(const float* __restrict__ feat0, const float* __restrict__ feat1,
                     const float* __restrict__ fc0_w, const float* __restrict__ fc0_b,
                     const float* __restrict__ fc1_w, const float* __restrict__ fc1_b,
                     const float* __restrict__ W0, const float* __restrict__ W1,
                     const int* __restrict__ dst,
                     _Float16* __restrict__ f0h, _Float16* __restrict__ f1h,
                     _Float16* __restrict__ Wc0t, _Float16* __restrict__ Wc1t,
                     _Float16* __restrict__ W1t, float* __restrict__ biasF,
                     int* __restrict__ cnt) {
    int idx = blockIdx.x * 256 + threadIdx.x;
    if (idx < E_N) {
        int m = idx >> 8, k = idx & 255;
        f0h[idx] = (m < 30000) ? (_Float16)feat0[(size_t)m * 256 + k] : (_Float16)0.f;
        return;
    }
    idx -= E_N;
    if (idx < F_N) {
        int m = idx >> 7, k = idx & 127;
        f1h[idx] = (m < 20000) ? (_Float16)feat1[(size_t)m * 128 + k] : (_Float16)0.f;
        return;
    }
    idx -= F_N;
    if (idx < A_N) {     // idx = k*512 + n, k<256
        int k = idx >> 9, n = idx & 511;
        float s = 0.f;
#pragma unroll 8
        for (int j = 0; j < 64; j++) s += fc0_w[k * 64 + j] * W0[j * 512 + n];
        Wc0t[n * 256 + k] = (_Float16)s;
        return;
    }
    idx -= A_N;
    if (idx < B_N) {     // idx = k*512 + n, k<128
        int k = idx >> 9, n = idx & 511;
        float s = 0.f;
#pragma unroll 8
        for (int j = 0; j < 64; j++) s += fc1_w[k * 64 + j] * W0[j * 512 + n];
        Wc1t[n * 128 + k] = (_Float16)s;
        return;
    }
    idx -= B_N;
    if (idx < C_N) {     // idx = k*512 + n
        int k = idx >> 9, n = idx & 511;
        W1t[n * 512 + k] = (_Float16)W1[k * 512 + n];
        return;
    }
    idx -= C_N;
    if (idx < D_N) {     // idx = t*512 + n
        int t = idx >> 9, n = idx & 511;
        const float* fb = t ? fc1_b : fc0_b;
        float s = 0.f;
#pragma unroll 8
        for (int j = 0; j < 64; j++) s += fb[j] * W0[j * 512 + n];
        biasF[t * 512 + n] = s;
        return;
    }
    idx -= D_N;
    if (idx < N_EDGES) atomicAdd(&cnt[dst[idx]], 1);
}

// ---------------------------------------------------------------------------
// CSR scan: parallel 3-kernel scan (proven)
// ---------------------------------------------------------------------------
#define NBLK_SCAN 196  // ceil(50000/256)

__global__ void scan_part(const int* __restrict__ cnt, int* __restrict__ part) {
    __shared__ int s[256];
    int i = blockIdx.x * 256 + threadIdx.x;
    s[threadIdx.x] = (i < N_NODES) ? cnt[i] : 0;
    __syncthreads();
    for (int off = 128; off; off >>= 1) {
        if (threadIdx.x < off) s[threadIdx.x] += s[threadIdx.x + off];
        __syncthreads();
    }
    if (threadIdx.x == 0) part[blockIdx.x] = s[0];
}

__global__ void scan_offs(int* __restrict__ part) {
    __shared__ int s[256];
    int tid = threadIdx.x;
    int v = (tid < NBLK_SCAN) ? part[tid] : 0;
    s[tid] = v;
    __syncthreads();
    for (int off = 1; off < 256; off <<= 1) {
        int x = (tid >= off) ? s[tid - off] : 0;
        __syncthreads();
        s[tid] += x;
        __syncthreads();
    }
    if (tid < NBLK_SCAN) part[tid] = s[tid] - v;  // exclusive
}

__global__ void scan_apply(const int* __restrict__ cnt, const int* __restrict__ part,
                           int* __restrict__ rp, int* __restrict__ cur) {
    __shared__ int s[256];
    int tid = threadIdx.x;
    int i = blockIdx.x * 256 + tid;
    int v = (i < N_NODES) ? cnt[i] : 0;
    s[tid] = v;
    __syncthreads();
    for (int off = 1; off < 256; off <<= 1) {
        int x = (tid >= off) ? s[tid - off] : 0;
        __syncthreads();
        s[tid] += x;
        __syncthreads();
    }
    if (i < N_NODES) {
        int excl = s[tid] - v + part[blockIdx.x];
        rp[i] = excl; cur[i] = excl;
    }
    if (i == 0) rp[N_NODES] = N_EDGES;
}

// ---------------------------------------------------------------------------
// GEMM tile body (device fn): 128x256 tile, 8 waves, BK=32, XOR-4 swizzle.
// Fused column-bias + el/er epilogue. Called from the heterogeneous kernel.
// ---------------------------------------------------------------------------
__device__ __forceinline__ void gemm_tile(
        const _Float16* __restrict__ A, const _Float16* __restrict__ Bt,
        _Float16* __restrict__ Cb, const float* __restrict__ al,
        const float* __restrict__ ar, const float* __restrict__ cbias,
        float* __restrict__ el, float* __restrict__ er,
        int M, int K, int row_off, int ytiles, int bid,
        _Float16* Asl, _Float16* Bsl) {
    int k8 = bid & 7, jj = bid >> 3;
    int y = k8 + 8 * (jj >> 1);
    if (y >= ytiles) return;
    int m0 = y * 128;
    int n0 = (jj & 1) * 256;
    int t = threadIdx.x;
    int lane = t & 63;
    int w = t >> 6;
    int wm = (w & 1) * 64, wn = (w >> 1) * 64;
    int l15 = lane & 15, quad = lane >> 4;
    f32x4 acc[4][4];
#pragma unroll
    for (int i = 0; i < 4; i++)
#pragma unroll
        for (int j = 0; j < 4; j++) acc[i][j] = (f32x4){0.f, 0.f, 0.f, 0.f};

    int fbA = t * 16;
    int rowA = fbA >> 6, kgA = ((fbA >> 4) & 3) ^ (rowA & 3);
    int fbB0 = t * 16;
    int fbB1 = fbB0 + 8192;
    int rowB0 = fbB0 >> 6, kgB0 = ((fbB0 >> 4) & 3) ^ (rowB0 & 3);
    int rowB1 = fbB1 >> 6, kgB1 = ((fbB1 >> 4) & 3) ^ (rowB1 & 3);

    for (int k0 = 0; k0 < K; k0 += 32) {
        GLD_LDS16(A + (size_t)(m0 + rowA) * K + k0 + kgA * 8, (char*)Asl + fbA);
        GLD_LDS16(Bt + (size_t)(n0 + rowB0) * K + k0 + kgB0 * 8, (char*)Bsl + fbB0);
        GLD_LDS16(Bt + (size_t)(n0 + rowB1) * K + k0 + kgB1 * 8, (char*)Bsl + fbB1);
        __syncthreads();
        f16x8 af[4], bfr[4];
#pragma unroll
        for (int i = 0; i < 4; i++) {
            int r = wm + i * 16 + l15;
            int kg = quad ^ (r & 3);
            af[i] = *(const f16x8*)(Asl + r * 32 + kg * 8);
        }
#pragma unroll
        for (int j = 0; j < 4; j++) {
            int r = wn + j * 16 + l15;
            int kg = quad ^ (r & 3);
            bfr[j] = *(const f16x8*)(Bsl + r * 32 + kg * 8);
        }
#pragma unroll
        for (int i = 0; i < 4; i++)
#pragma unroll
            for (int j = 0; j < 4; j++)
                acc[i][j] = __builtin_amdgcn_mfma_f32_16x16x32_f16(af[i], bfr[j], acc[i][j], 0, 0, 0);
        __syncthreads();
    }
    float cb[4];
#pragma unroll
    for (int j = 0; j < 4; j++)
        cb[j] = cbias ? cbias[n0 + wn + j * 16 + l15] : 0.f;
    // C/D layout: col = l15, row = quad*4 + reg  [m89/m91 verified]
#pragma unroll
    for (int i = 0; i < 4; i++) {
        int rbase = m0 + wm + i * 16 + quad * 4;
#pragma unroll
        for (int j = 0; j < 4; j++) {
            int col = n0 + wn + j * 16 + l15;
#pragma unroll
            for (int r = 0; r < 4; r++) {
                int row = rbase + r;
                if (row < M)
                    Cb[(size_t)(row_off + row) * HD + col] = (_Float16)(acc[i][j][r] + cb[j]);
            }
        }
    }
    int h = (n0 + wn) >> 6;
    float alv[4], arv[4];
#pragma unroll
    for (int j = 0; j < 4; j++) {
        alv[j] = al[h * 64 + j * 16 + l15];
        arv[j] = ar[h * 64 + j * 16 + l15];
    }
#pragma unroll
    for (int i = 0; i < 4; i++) {
#pragma unroll
        for (int r = 0; r < 4; r++) {
            float sl = 0.f, sr = 0.f;
#pragma unroll
            for (int j = 0; j < 4; j++) {
                float v = acc[i][j][r] + cb[j];
                sl += v * alv[j]; sr += v * arv[j];
            }
#pragma unroll
            for (int mk = 1; mk < 16; mk <<= 1) {
                sl += __shfl_xor(sl, mk);
                sr += __shfl_xor(sr, mk);
            }
            int row = m0 + wm + i * 16 + quad * 4 + r;
            if (l15 == 0 && row < M) {
                el[(size_t)(row_off + row) * HEADS + h] = sl;
                er[(size_t)(row_off + row) * HEADS + h] = sr;
            }
        }
    }
}

// ---------------------------------------------------------------------------
// Heterogeneous fused launch: scatter blocks + L0a GEMM blocks + L0b blocks.
// Scatter (CSR-dep) and L0 GEMMs (prep-dep) are independent -> co-scheduled,
// scatter's random-atomic latency hides under MFMA work.
// ---------------------------------------------------------------------------
#define SCAT_BLKS ((N_EDGES + 511) / 512)   // 977
#define G0A_BLKS (8 * 2 * ((235 + 7) / 8))  // 480
#define G0B_BLKS (8 * 2 * ((157 + 7) / 8))  // 320

__global__ __launch_bounds__(512) void scatter_gemm0(
        const int* __restrict__ src, const int* __restrict__ dst,
        int* __restrict__ cursor, int* __restrict__ srcs,
        const _Float16* __restrict__ f0h, const _Float16* __restrict__ Wc0t,
        const _Float16* __restrict__ f1h, const _Float16* __restrict__ Wc1t,
        _Float16* __restrict__ featA, const float* __restrict__ al0,
        const float* __restrict__ ar0, const float* __restrict__ biasF,
        float* __restrict__ el, float* __restrict__ er) {
    __shared__ _Float16 Asl[128 * 32];
    __shared__ _Float16 Bsl[256 * 32];
    int bid = blockIdx.x;
    if (bid < SCAT_BLKS) {
        int t = bid * 512 + threadIdx.x;
        if (t < N_EDGES) {
            int pos = atomicAdd(&cursor[dst[t]], 1);
            srcs[pos] = src[t];
        }
        return;
    }
    bid -= SCAT_BLKS;
    if (bid < G0A_BLKS) {
        gemm_tile(f0h, Wc0t, featA, al0, ar0, biasF, el, er,
                  30000, 256, 0, 235, bid, Asl, Bsl);
        return;
    }
    bid -= G0A_BLKS;
    gemm_tile(f1h, Wc1t, featA, al0, ar0, biasF + 512, el, er,
              20000, 128, 30000, 157, bid, Asl, Bsl);
}

// ---------------------------------------------------------------------------
// Standalone wide GEMM (layer 1)
// ---------------------------------------------------------------------------
__global__ __launch_bounds__(512) void gemm_mfma_wide(const _Float16* __restrict__ A,
                                                      const _Float16* __restrict__ Bt,
                                                      _Float16* __restrict__ Cb,
                                                      const float* __restrict__ al,
                                                      const float* __restrict__ ar,
                                                      float* __restrict__ el,
                                                      float* __restrict__ er,
                                                      int M, int K, int ytiles) {
    __shared__ _Float16 Asl[128 * 32];
    __shared__ _Float16 Bsl[256 * 32];
    gemm_tile(A, Bt, Cb, al, ar, nullptr, el, er, M, K, 0, ytiles,
              blockIdx.x, Asl, Bsl);
}

// ---------------------------------------------------------------------------
// Fused edge softmax + aggregation, one wave per block (64 threads).
// Wave-private LDS handoff, no block barrier. Phase B: 4x-unrolled gather.
// ---------------------------------------------------------------------------
__global__ __launch_bounds__(64) void attn_agg(
        const int* __restrict__ rp, const int* __restrict__ srcs,
        const float* __restrict__ el, const float* __restrict__ er,
        const _Float16* __restrict__ feat, const float* __restrict__ bias,
        _Float16* __restrict__ out) {
    __shared__ float aS[592];   // [0..575] alpha (p*9+h), [576..583] inv, [584..591] m
    __shared__ int   sS[64];
    int lane = threadIdx.x;
    int n    = blockIdx.x;
    int s0 = rp[n], s1 = rp[n + 1];
    int deg = s1 - s0;
    float er8[8];
    {
        f32x4 a = *(const f32x4*)(er + (size_t)n * 8);
        f32x4 b = *(const f32x4*)(er + (size_t)n * 8 + 4);
        er8[0]=a[0]; er8[1]=a[1]; er8[2]=a[2]; er8[3]=a[3];
        er8[4]=b[0]; er8[5]=b[1]; er8[6]=b[2]; er8[7]=b[3];
    }
    bool fast = (deg <= 64);
    if (fast) {
        bool act = lane < deg;
        int sp = act ? srcs[s0 + lane] : 0;
        sS[lane] = sp;
        f32x4 ea = {0.f,0.f,0.f,0.f}, eb = {0.f,0.f,0.f,0.f};
        if (act) {
            ea = *(const f32x4*)(el + (size_t)sp * 8);
            eb = *(const f32x4*)(el + (size_t)sp * 8 + 4);
        }
        float e8[8] = {ea[0],ea[1],ea[2],ea[3],eb[0],eb[1],eb[2],eb[3]};
#pragma unroll
        for (int h = 0; h < 8; h++) {
            float e = e8[h] + er8[h];
            e = e > 0.f ? e : 0.2f * e;
            e8[h] = act ? e : -1e30f;
        }
#pragma unroll
        for (int h = 0; h < 8; h++) {
            float mm = e8[h];
#pragma unroll
            for (int mk = 1; mk < 64; mk <<= 1) mm = fmaxf(mm, __shfl_xor(mm, mk));
            float pv = act ? __expf(e8[h] - mm) : 0.f;
            float ss = pv;
#pragma unroll
            for (int mk = 1; mk < 64; mk <<= 1) ss += __shfl_xor(ss, mk);
            aS[lane * 9 + h] = pv * (1.f / fmaxf(ss, 1e-9f));  // pre-scaled alpha
        }
    } else {
        float m8[8], s8[8];
#pragma unroll
        for (int h = 0; h < 8; h++) { m8[h] = -1e30f; s8[h] = 0.f; }
        for (int base = s0; base < s1; base += 64) {
            bool act = base + lane < s1;
            int sp = act ? srcs[base + lane] : 0;
            f32x4 ea = {0.f,0.f,0.f,0.f}, eb = {0.f,0.f,0.f,0.f};
            if (act) {
                ea = *(const f32x4*)(el + (size_t)sp * 8);
                eb = *(const f32x4*)(el + (size_t)sp * 8 + 4);
            }
            float ev[8] = {ea[0],ea[1],ea[2],ea[3],eb[0],eb[1],eb[2],eb[3]};
#pragma unroll
            for (int h = 0; h < 8; h++) {
                float e = ev[h] + er8[h];
                e = e > 0.f ? e : 0.2f * e;
                e = act ? e : -1e30f;
                float cm = e;
#pragma unroll
                for (int mk = 1; mk < 64; mk <<= 1) cm = fmaxf(cm, __shfl_xor(cm, mk));
                float nm = fmaxf(m8[h], cm);
                float pv = act ? __expf(e - nm) : 0.f;
#pragma unroll
                for (int mk = 1; mk < 64; mk <<= 1) pv += __shfl_xor(pv, mk);
                s8[h] = s8[h] * __expf(m8[h] - nm) + pv;
                m8[h] = nm;
            }
        }
        if (lane == 0) {
#pragma unroll
            for (int h = 0; h < 8; h++) {
                aS[576 + h] = 1.f / fmaxf(s8[h], 1e-9f);
                aS[584 + h] = m8[h];
            }
        }
    }
    // wave-private LDS handoff (lockstep wave + compiler lgkmcnt ordering)
    __builtin_amdgcn_wave_barrier();
    int hh = lane >> 3, d0 = (lane & 7) * 8;   // lane*8 = hh*64 + d0
    h8v z = {(_Float16)0, (_Float16)0, (_Float16)0, (_Float16)0,
             (_Float16)0, (_Float16)0, (_Float16)0, (_Float16)0};
    h8v acc0 = z, acc1 = z, acc2 = z, acc3 = z;
    const _Float16* colbase = feat + hh * 64 + d0;
    if (fast) {
        int p = 0;
        for (; p + 4 <= deg; p += 4) {
            int spa = sS[p],     spb = sS[p + 1];
            int spc = sS[p + 2], spd = sS[p + 3];
            _Float16 aa = (_Float16)aS[p * 9 + hh];
            _Float16 ab = (_Float16)aS[(p + 1) * 9 + hh];
            _Float16 ac = (_Float16)aS[(p + 2) * 9 + hh];
            _Float16 ad = (_Float16)aS[(p + 3) * 9 + hh];
            h8v fa = *(const h8v*)(colbase + (size_t)spa * HD);
            h8v fb = *(const h8v*)(colbase + (size_t)spb * HD);
            h8v fc = *(const h8v*)(colbase + (size_t)spc * HD);
            h8v fd = *(const h8v*)(colbase + (size_t)spd * HD);
            h8v a8a = {aa, aa, aa, aa, aa, aa, aa, aa};
            h8v a8b = {ab, ab, ab, ab, ab, ab, ab, ab};
            h8v a8c = {ac, ac, ac, ac, ac, ac, ac, ac};
            h8v a8d = {ad, ad, ad, ad, ad, ad, ad, ad};
            acc0 += a8a * fa;
            acc1 += a8b * fb;
            acc2 += a8c * fc;
            acc3 += a8d * fd;
        }
        for (; p < deg; p++) {
            int sp = sS[p];
            _Float16 ah = (_Float16)aS[p * 9 + hh];
            h8v a8 = {ah, ah, ah, ah, ah, ah, ah, ah};
            h8v f = *(const h8v*)(colbase + (size_t)sp * HD);
            acc0 += a8 * f;
        }
    } else {
        float inv_l = aS[576 + hh];
        float m_l   = aS[584 + hh];
        float ern_l = er[(size_t)n * 8 + hh];
        for (int p = s0; p < s1; p++) {
            int sp = srcs[p];
            float e = el[(size_t)sp * 8 + hh] + ern_l;
            e = e > 0.f ? e : 0.2f * e;
            _Float16 ah = (_Float16)(__expf(e - m_l) * inv_l);
            h8v a8 = {ah, ah, ah, ah, ah, ah, ah, ah};
            h8v f = *(const h8v*)(colbase + (size_t)sp * HD);
            acc0 += a8 * f;
        }
    }
    acc0 += acc1; acc2 += acc3; acc0 += acc2;
    float4 b0v = *(const float4*)(bias + lane * 8);
    float4 b1v = *(const float4*)(bias + lane * 8 + 4);
    float bb[8] = {b0v.x,b0v.y,b0v.z,b0v.w,b1v.x,b1v.y,b1v.z,b1v.w};
    h8v o;
#pragma unroll
    for (int j = 0; j < 8; j++) {
        float x = (float)acc0[j] + bb[j];
        x = x > 0.f ? x : __expf(x) - 1.f;
        o[j] = (_Float16)x;
    }
    *(h8v*)(out + (size_t)n * HD + lane * 8) = o;
}

// ---------------------------------------------------------------------------
// layer 2 GEMM (N=10) from f16 A, fused el2/er2 epilogue
// ---------------------------------------------------------------------------
__global__ __launch_bounds__(256) void gemm_n10v2(
        const _Float16* __restrict__ A, const float* __restrict__ B,
        const float* __restrict__ al2, const float* __restrict__ ar2,
        float* __restrict__ C, float* __restrict__ el, float* __restrict__ er) {
    __shared__ float Bs[512 * 11];
    int t = threadIdx.x;
    for (int i = t; i < 512 * NCLS; i += 256) {
        int k = i / NCLS, c = i - k * NCLS;
        Bs[k * 11 + c] = B[i];
    }
    __syncthreads();
    int lane = t & 63;
    int m = blockIdx.x * 4 + (t >> 6);
    float acc[NCLS];
#pragma unroll
    for (int c = 0; c < NCLS; c++) acc[c] = 0.f;
    const _Float16* a = A + (size_t)m * HD;
#pragma unroll
    for (int j = 0; j < 8; j++) {
        float av = (float)a[j * 64 + lane];
        const float* br = Bs + (j * 64 + lane) * 11;
#pragma unroll
        for (int c = 0; c < NCLS; c++) acc[c] += av * br[c];
    }
#pragma unroll
    for (int c = 0; c < NCLS; c++)
#pragma unroll
        for (int mk = 1; mk < 64; mk <<= 1) acc[c] += __shfl_xor(acc[c], mk);
    if (lane == 0) {
        float e1 = 0.f, e2 = 0.f;
#pragma unroll
        for (int c = 0; c < NCLS; c++) { e1 += acc[c] * al2[c]; e2 += acc[c] * ar2[c]; }
        el[m] = e1; er[m] = e2;
#pragma unroll
        for (int c = 0; c < NCLS; c++) C[(size_t)m * NCLS + c] = acc[c];
    }
}

// ---------------------------------------------------------------------------
// layer 2 fused softmax+aggregation (H=1, D=10), one wave per block
// ---------------------------------------------------------------------------
__global__ __launch_bounds__(64) void attn2_agg2(
        const int* __restrict__ rp, const int* __restrict__ srcs,
        const float* __restrict__ el, const float* __restrict__ er,
        const float* __restrict__ feat2, const float* __restrict__ b2,
        float* __restrict__ out) {
    int lane = threadIdx.x;
    int n = blockIdx.x;
    int s0 = rp[n], s1 = rp[n + 1], deg = s1 - s0;
    float ern = er[n];
    float facc[NCLS];
#pragma unroll
    for (int c = 0; c < NCLS; c++) facc[c] = 0.f;
    if (deg <= 64) {
        bool act = lane < deg;
        int sp = act ? srcs[s0 + lane] : 0;
        float e = act ? el[sp] + ern : 0.f;
        e = e > 0.f ? e : 0.2f * e;
        if (!act) e = -1e30f;
        float mm = e;
#pragma unroll
        for (int mk = 1; mk < 64; mk <<= 1) mm = fmaxf(mm, __shfl_xor(mm, mk));
        float pv = act ? __expf(e - mm) : 0.f;
        float ss = pv;
#pragma unroll
        for (int mk = 1; mk < 64; mk <<= 1) ss += __shfl_xor(ss, mk);
        float a = pv / fmaxf(ss, 1e-9f);
        if (act) {
#pragma unroll
            for (int c = 0; c < NCLS; c++) facc[c] = a * feat2[(size_t)sp * NCLS + c];
        }
    } else {
        float mm = -1e30f, ssum = 0.f;
        for (int base = s0; base < s1; base += 64) {
            bool act = base + lane < s1;
            int sp = act ? srcs[base + lane] : 0;
            float e = act ? el[sp] + ern : 0.f;
            e = e > 0.f ? e : 0.2f * e;
            if (!act) e = -1e30f;
            float cm = e;
#pragma unroll
            for (int mk = 1; mk < 64; mk <<= 1) cm = fmaxf(cm, __shfl_xor(cm, mk));
            float nm = fmaxf(mm, cm);
            float pv = act ? __expf(e - nm) : 0.f;
#pragma unroll
            for (int mk = 1; mk < 64; mk <<= 1) pv += __shfl_xor(pv, mk);
            ssum = ssum * __expf(mm - nm) + pv;
            mm = nm;
        }
        float inv = 1.f / fmaxf(ssum, 1e-9f);
        for (int base = s0; base < s1; base += 64) {
            bool act = base + lane < s1;
            int sp = act ? srcs[base + lane] : 0;
            float e = act ? el[sp] + ern : 0.f;
            e = e > 0.f ? e : 0.2f * e;
            float a = act ? __expf(e - mm) * inv : 0.f;
            if (act) {
#pragma unroll
                for (int c = 0; c < NCLS; c++) facc[c] += a * feat2[(size_t)sp * NCLS + c];
            }
        }
    }
#pragma unroll
    for (int c = 0; c < NCLS; c++)
#pragma unroll
        for (int mk = 1; mk < 64; mk <<= 1) facc[c] += __shfl_xor(facc[c], mk);
    if (lane == 0) {
#pragma unroll
        for (int c = 0; c < NCLS; c++) out[(size_t)n * NCLS + c] = facc[c] + b2[c];
    }
}

// ---------------------------------------------------------------------------
extern "C" void kernel_launch(void* const* d_in, const int* in_sizes, int n_in,
                              void* d_out, int out_size, void* d_ws, size_t ws_size,
                              hipStream_t stream) {
    const float* feat0 = (const float*)d_in[0];
    const float* feat1 = (const float*)d_in[1];
    const float* fc0_w = (const float*)d_in[2];
    const float* fc0_b = (const float*)d_in[3];
    const float* fc1_w = (const float*)d_in[4];
    const float* fc1_b = (const float*)d_in[5];
    const float* W0    = (const float*)d_in[6];
    const float* al0   = (const float*)d_in[7];
    const float* ar0   = (const float*)d_in[8];
    const float* b0    = (const float*)d_in[9];
    const float* W1    = (const float*)d_in[10];
    const float* al1   = (const float*)d_in[11];
    const float* ar1   = (const float*)d_in[12];
    const float* b1    = (const float*)d_in[13];
    const float* W2    = (const float*)d_in[14];
    const float* al2   = (const float*)d_in[15];
    const float* ar2   = (const float*)d_in[16];
    const float* b2    = (const float*)d_in[17];
    const int* eidx    = (const int*)d_in[18];
    const int* src = eidx;
    const int* dst = eidx + N_EDGES;
    float* out = (float*)d_out;

    char* ws = (char*)d_ws;
    size_t off = 0;
    auto alloc = [&](size_t bytes) { size_t o = off; off = (off + bytes + 255) & ~(size_t)255; return o; };

    _Float16* featA = (_Float16*)(ws + alloc((size_t)M_PAD * HD * 2));
    _Float16* aggh  = (_Float16*)(ws + alloc((size_t)M_PAD * HD * 2));
    _Float16* f0h   = (_Float16*)(ws + alloc((size_t)F0ROWS * 256 * 2));
    _Float16* f1h   = (_Float16*)(ws + alloc((size_t)F1ROWS * 128 * 2));
    float*    feat2 = (float*)(ws + alloc((size_t)N_NODES * NCLS * 4));
    float*    el    = (float*)(ws + alloc((size_t)N_NODES * HEADS * 4));
    float*    er    = (float*)(ws + alloc((size_t)N_NODES * HEADS * 4));
    float*    el2   = (float*)(ws + alloc((size_t)N_NODES * 4));
    float*    er2   = (float*)(ws + alloc((size_t)N_NODES * 4));
    float*    biasF = (float*)(ws + alloc(1024 * 4));
    int*      cnt   = (int*)  (ws + alloc((size_t)N_NODES * 4));
    int*      rp    = (int*)  (ws + alloc((size_t)(N_NODES + 1) * 4));
    int*      cur   = (int*)  (ws + alloc((size_t)N_NODES * 4));
    int*      srcs  = (int*)  (ws + alloc((size_t)N_EDGES * 4));
    int*      part  = (int*)  (ws + alloc(1024));
    _Float16* Wc0t  = (_Float16*)(ws + alloc(512 * 256 * 2));
    _Float16* Wc1t  = (_Float16*)(ws + alloc(512 * 128 * 2));
    _Float16* W1t   = (_Float16*)(ws + alloc(512 * 512 * 2));

    // --- cnt zero, then prep (weight folds + casts + count fused) ---
    hipMemsetAsync(cnt, 0, N_NODES * sizeof(int), stream);
    prep<<<(PREP_TOTAL + 255) / 256, 256, 0, stream>>>(
        feat0, feat1, fc0_w, fc0_b, fc1_w, fc1_b, W0, W1, dst,
        f0h, f1h, Wc0t, Wc1t, W1t, biasF, cnt);

    // --- CSR scan ---
    scan_part<<<NBLK_SCAN, 256, 0, stream>>>(cnt, part);
    scan_offs<<<1, 256, 0, stream>>>(part);
    scan_apply<<<NBLK_SCAN, 256, 0, stream>>>(cnt, part, rp, cur);

    // --- fused: scatter + layer-0 GEMMs (independent work, one launch) ---
    scatter_gemm0<<<SCAT_BLKS + G0A_BLKS + G0B_BLKS, 512, 0, stream>>>(
        src, dst, cur, srcs, f0h, Wc0t, f1h, Wc1t, featA, al0, ar0, biasF, el, er);

    attn_agg<<<N_NODES, 64, 0, stream>>>(rp, srcs, el, er, featA, b0, aggh);

    // --- layer 1 ---
    int g1 = 8 * 2 * ((YTILES_L1 + 7) / 8);  // 784
    gemm_mfma_wide<<<g1, 512, 0, stream>>>(aggh, W1t, featA, al1, ar1, el, er,
                                           N_NODES, HD, YTILES_L1);
    attn_agg<<<N_NODES, 64, 0, stream>>>(rp, srcs, el, er, featA, b1, aggh);

    // --- layer 2 ---
    gemm_n10v2<<<N_NODES / 4, 256, 0, stream>>>(aggh, W2, al2, ar2, feat2, el2, er2);
    attn2_agg2<<<N_NODES, 64, 0, stream>>>(rp, srcs, el2, er2, feat2, b2, out);
}